// Round 10
// baseline (114.262 us; speedup 1.0000x reference)
//
#include <hip/hip_runtime.h>
#include <stdint.h>

#define NEG_SLOPE 0.2f
#define DHID 256
#define BSZ_SHIFT 10                 // 1024 nodes per bucket
#define BSZ (1 << BSZ_SHIFT)
#define MAXNB 128                    // supports N <= 131072
#define PSUB 16                      // accumulate blocks per bucket
#define SCHUNK 4096                  // edges per scatter block (512 thr)
#define KSUB 4                       // sub-blocks per graph in pooling

__device__ __forceinline__ float lrelu(float e) {
    return (e >= 0.0f) ? e : NEG_SLOPE * e;
}
__device__ __forceinline__ float dot4(float4 a, float4 b) {
    return a.x * b.x + a.y * b.y + a.z * b.z + a.w * b.w;
}

// ---------------------------------------------------------------------------
// M1: three independent block roles in ONE kernel (they share no data):
//   [0, nScat)                : edge scatter (latency-bound)
//   [nScat, nScat+nRowBlk)    : h = x·W rows, 4 rows/wave, 32 rows/block (BW)
//   [.., +nBndBlk)            : segment bounds from sorted batch
// cursor/gsum are pre-zeroed by hipMemsetAsync. Scatter blocks first so both
// latency- and BW-bound waves co-resident from t=0 (wave-level overlap, m114).
// Scatter rank trick: hist-pass atomicAdd return value IS the intra-block
// rank -> no second LDS-atomic pass.
// NOTE: no device-scope fences (R8: per-block __threadfence = L2 storm).
// ---------------------------------------------------------------------------
__global__ __launch_bounds__(512) void kM1(
    const float* __restrict__ x, const float* __restrict__ W,
    float* __restrict__ h, int N,
    const int* __restrict__ batch, int* __restrict__ start, int G,
    const int* __restrict__ src, const int* __restrict__ dst, int E, int NB,
    int* __restrict__ cursor, uint32_t* __restrict__ pairs, int CAP,
    int nScat, int nRowBlk)
{
    __shared__ int cnt[MAXNB];
    __shared__ int loff[MAXNB];
    __shared__ int base_g[MAXNB];
    __shared__ uint32_t buf[SCHUNK];
    __shared__ uint8_t binOf[SCHUNK];

    int bid = blockIdx.x;
    int t = threadIdx.x;

    if (bid < nScat) {
        // ------------------- scatter path -------------------
        int e0 = bid * SCHUNK;
        int e1 = min(e0 + SCHUNK, E);
        int nch = e1 - e0;

        int sv[8], dv[8], rk[8];
#pragma unroll
        for (int k = 0; k < 8; ++k) {
            int e = e0 + k * 512 + t;
            if (e < e1) { sv[k] = src[e]; dv[k] = dst[e]; }
        }
        for (int q = t; q < MAXNB; q += 512) cnt[q] = 0;
        __syncthreads();
#pragma unroll
        for (int k = 0; k < 8; ++k) {
            int e = e0 + k * 512 + t;
            if (e < e1) rk[k] = atomicAdd(&cnt[dv[k] >> BSZ_SHIFT], 1);
        }
        __syncthreads();
        // exclusive scan of cnt[0..127] by wave 0 (two chained 64-lane scans)
        if (t < 64) {
            int v0 = cnt[t], v1 = cnt[64 + t];
            int s0 = v0, s1 = v1;
#pragma unroll
            for (int d = 1; d < 64; d <<= 1) {
                int u0 = __shfl_up(s0, d);
                int u1 = __shfl_up(s1, d);
                if (t >= d) { s0 += u0; s1 += u1; }
            }
            int tot0 = __shfl(s0, 63);
            loff[t]      = s0 - v0;
            loff[64 + t] = s1 + tot0 - v1;
        }
        __syncthreads();
        for (int q = t; q < MAXNB; q += 512)
            if (q < NB && cnt[q] > 0) base_g[q] = atomicAdd(&cursor[q], cnt[q]);
        __syncthreads();
#pragma unroll
        for (int k = 0; k < 8; ++k) {
            int e = e0 + k * 512 + t;
            if (e < e1) {
                int bin = dv[k] >> BSZ_SHIFT;
                int q = loff[bin] + rk[k];
                buf[q] = ((uint32_t)sv[k] << BSZ_SHIFT) |
                         (uint32_t)(dv[k] & (BSZ - 1));
                binOf[q] = (uint8_t)bin;
            }
        }
        __syncthreads();
        for (int q = t; q < nch; q += 512) {
            int b = binOf[q];
            pairs[(size_t)b * CAP + base_g[b] + (q - loff[b])] = buf[q];
        }
        return;
    }

    if (bid < nScat + nRowBlk) {
        // ------------------- h rows path -------------------
        int rb = bid - nScat;
        int wave = t >> 6;
        int lane = t & 63;
        int r = lane >> 4;                  // row within wave (0..3)
        int c = lane & 15;                  // 16 lanes per row
        int row = rb * 32 + wave * 4 + r;
        if (row >= N) return;               // 16-lane group uniform

        float4 wv0 = *(const float4*)(W + c * 4);
        float4 wv1 = *(const float4*)(W + 64 + c * 4);
        float4 wv2 = *(const float4*)(W + 128 + c * 4);
        float4 wv3 = *(const float4*)(W + 192 + c * 4);
        const float* xr = x + (size_t)row * DHID;
        float4 a0 = *(const float4*)(xr + c * 4);
        float4 a1 = *(const float4*)(xr + 64 + c * 4);
        float4 a2 = *(const float4*)(xr + 128 + c * 4);
        float4 a3 = *(const float4*)(xr + 192 + c * 4);
        float s = dot4(a0, wv0) + dot4(a1, wv1) + dot4(a2, wv2) + dot4(a3, wv3);
        s += __shfl_xor(s, 1);
        s += __shfl_xor(s, 2);
        s += __shfl_xor(s, 4);
        s += __shfl_xor(s, 8);              // stays inside the 16-lane group
        if (c == 0) h[row] = s;
        return;
    }

    // ------------------- bounds path -------------------
    {
        int rb = bid - nScat - nRowBlk;
        int i = rb * 512 + t;
        if (i >= N) return;
        int b = batch[i];
        if (i == 0) {
            for (int g = 0; g <= b; ++g) start[g] = 0;
        } else {
            int bp = batch[i - 1];
            for (int g = bp + 1; g <= b; ++g) start[g] = i;
        }
        if (i == N - 1) {
            for (int g = b + 1; g <= G; ++g) start[g] = N;
        }
    }
}

// ---------------------------------------------------------------------------
// k_accum: block = (bucket b, sub s). h[src] gathered from L2-resident table;
// h[dst] from LDS slice; num/denom via native LDS float atomics.
// partials layout: [(b*PSUB+s)][2][BSZ]
// ---------------------------------------------------------------------------
__global__ __launch_bounds__(256) void k_accum(
    const uint32_t* __restrict__ pairs, const int* __restrict__ cursor,
    const float* __restrict__ h,
    const float* __restrict__ att_src, const float* __restrict__ att_dst,
    float* __restrict__ partials, int N, int CAP)
{
    __shared__ float dacc[BSZ];
    __shared__ float nacc[BSZ];
    __shared__ float hbuf[BSZ];
    int b = blockIdx.x / PSUB;
    int s = blockIdx.x % PSUB;
    int base = b << BSZ_SHIFT;

    for (int t = threadIdx.x; t < BSZ; t += 256) {
        dacc[t] = 0.0f; nacc[t] = 0.0f;
        int gi = base + t;
        hbuf[t] = (gi < N) ? h[gi] : 0.0f;
    }
    __syncthreads();

    int count = cursor[b];
    int per = (count + PSUB - 1) / PSUB;
    int i0 = s * per;
    int i1 = min(i0 + per, count);

    float as = att_src[0], ad = att_dst[0];
    const uint32_t* bp = pairs + (size_t)b * CAP;
    for (int i = i0 + threadIdx.x; i < i1; i += 256) {
        uint32_t pr = bp[i];
        int ld = (int)(pr & (BSZ - 1));
        float hs = h[pr >> BSZ_SHIFT];
        float w = __expf(lrelu(as * hs + ad * hbuf[ld]));
        atomicAdd(&dacc[ld], w);
        atomicAdd(&nacc[ld], w * hs);
    }
    __syncthreads();
    float* out = partials + ((size_t)blockIdx.x * 2) * BSZ;
    for (int t = threadIdx.x; t < BSZ; t += 256) {
        out[t]       = dacc[t];
        out[BSZ + t] = nacc[t];
    }
}

// ---------------------------------------------------------------------------
// k3: merge partials + self-loop, escore = exp(num/denom + bias);
// LDS-binned gsum reduction (batch sorted).
// ---------------------------------------------------------------------------
__global__ __launch_bounds__(256) void k3_scores_p(
    const float* __restrict__ partials, const float* __restrict__ h,
    const float* __restrict__ att_src, const float* __restrict__ att_dst,
    const float* __restrict__ bias, const int* __restrict__ batch,
    float* __restrict__ escore, float* __restrict__ gsum, int N)
{
    __shared__ float bins[64];
    __shared__ int bbase_s;
    int i = blockIdx.x * 256 + threadIdx.x;
    if (threadIdx.x == 0) {
        int i0 = blockIdx.x * 256;
        bbase_s = batch[i0 < N ? i0 : N - 1];
    }
    for (int t = threadIdx.x; t < 64; t += 256) bins[t] = 0.0f;

    float w = 0.0f;
    int b = -1;
    if (i < N) {
        int bk = i >> BSZ_SHIFT;
        int pos = i & (BSZ - 1);
        float dsum = 0.0f, nsum = 0.0f;
#pragma unroll
        for (int p = 0; p < PSUB; ++p) {
            const float* pp = partials + ((size_t)(bk * PSUB + p) * 2) * BSZ;
            dsum += pp[pos];
            nsum += pp[BSZ + pos];
        }
        float hi = h[i];
        float e0 = lrelu((att_src[0] + att_dst[0]) * hi);
        float ws = __expf(e0);
        dsum += ws;
        nsum += ws * hi;
        float xc = nsum / (dsum + 1e-16f) + bias[0];
        w = __expf(xc);
        escore[i] = w;
        b = batch[i];
    }
    __syncthreads();
    if (i < N) {
        int off = b - bbase_s;
        if (off >= 0 && off < 64) atomicAdd(&bins[off], w);
        else                      atomicAdd(&gsum[b], w);
    }
    __syncthreads();
    for (int t = threadIdx.x; t < 64; t += 256)
        if (bins[t] != 0.0f) atomicAdd(&gsum[bbase_s + t], bins[t]);
}

// ---------------------------------------------------------------------------
// k4: KSUB blocks per graph; 4-deep unrolled weighted sum into gxp[s][G][DHID].
// ---------------------------------------------------------------------------
__global__ __launch_bounds__(256) void k4_pool(
    const float* __restrict__ x, const float* __restrict__ escore,
    const float* __restrict__ gsum, const int* __restrict__ start,
    float* __restrict__ gxp, int G)
{
    int g = blockIdx.x >> 2;        // KSUB == 4
    int s = blockIdx.x & 3;
    int st = start[g], en = start[g + 1];
    float inv = 1.0f / (gsum[g] + 1e-16f);
    int tid    = threadIdx.x;
    int col4   = (tid & 63) << 2;
    int rowOff = tid >> 6;          // 0..3

    float4 acc = make_float4(0.f, 0.f, 0.f, 0.f);
    int i = st + s * 4 + rowOff;
    for (; i + 48 < en; i += 64) {
        float sc0 = escore[i] * inv;
        float sc1 = escore[i + 16] * inv;
        float sc2 = escore[i + 32] * inv;
        float sc3 = escore[i + 48] * inv;
        float4 v0 = *(const float4*)(x + (size_t)i * DHID + col4);
        float4 v1 = *(const float4*)(x + (size_t)(i + 16) * DHID + col4);
        float4 v2 = *(const float4*)(x + (size_t)(i + 32) * DHID + col4);
        float4 v3 = *(const float4*)(x + (size_t)(i + 48) * DHID + col4);
        acc.x += v0.x * sc0 + v1.x * sc1 + v2.x * sc2 + v3.x * sc3;
        acc.y += v0.y * sc0 + v1.y * sc1 + v2.y * sc2 + v3.y * sc3;
        acc.z += v0.z * sc0 + v1.z * sc1 + v2.z * sc2 + v3.z * sc3;
        acc.w += v0.w * sc0 + v1.w * sc1 + v2.w * sc2 + v3.w * sc3;
    }
    for (; i < en; i += 16) {
        float sc = escore[i] * inv;
        float4 v = *(const float4*)(x + (size_t)i * DHID + col4);
        acc.x += v.x * sc; acc.y += v.y * sc;
        acc.z += v.z * sc; acc.w += v.w * sc;
    }

    __shared__ float4 red[256];
    red[tid] = acc;
    __syncthreads();
    if (tid < 64) {
        float4 a = red[tid], b = red[tid + 64], c = red[tid + 128], d = red[tid + 192];
        float4 r;
        r.x = a.x + b.x + c.x + d.x;
        r.y = a.y + b.y + c.y + d.y;
        r.z = a.z + b.z + c.z + d.z;
        r.w = a.w + b.w + c.w + d.w;
        *(float4*)(gxp + ((size_t)s * G + g) * DHID + col4) = r;
    }
}

// ---------------------------------------------------------------------------
// k5: merge the KSUB pooling partials into gx.
// ---------------------------------------------------------------------------
__global__ __launch_bounds__(256) void k5_merge(
    const float* __restrict__ gxp, float* __restrict__ gx, int total)
{
    int j = blockIdx.x * 256 + threadIdx.x;
    if (j < total)
        gx[j] = gxp[j] + gxp[total + j] + gxp[2 * total + j] + gxp[3 * total + j];
}

// ---------------------------------------------------------------------------
// Fallback path (ws too small): direct global atomics.
// ---------------------------------------------------------------------------
__global__ __launch_bounds__(256) void k0_zero_fb(float* __restrict__ p, int n) {
    int i = blockIdx.x * 256 + threadIdx.x;
    if (i < n) p[i] = 0.0f;
}
__global__ __launch_bounds__(256) void k2_edges_fb(
    const int* __restrict__ src, const int* __restrict__ dst,
    const float* __restrict__ h,
    const float* __restrict__ att_src, const float* __restrict__ att_dst,
    float* __restrict__ denom, float* __restrict__ num, int E)
{
    int i = blockIdx.x * 256 + threadIdx.x;
    if (i >= E) return;
    int s = src[i], d = dst[i];
    float as = att_src[0], ad = att_dst[0];
    float hs = h[s];
    float w = expf(lrelu(as * hs + ad * h[d]));
    atomicAdd(&denom[d], w);
    atomicAdd(&num[d],   w * hs);
}
__global__ __launch_bounds__(256) void k3_scores_fb(
    const float* __restrict__ denom, const float* __restrict__ num,
    const float* __restrict__ h,
    const float* __restrict__ att_src, const float* __restrict__ att_dst,
    const float* __restrict__ bias, const int* __restrict__ batch,
    float* __restrict__ escore, float* __restrict__ gsum, int N)
{
    __shared__ float bins[64];
    __shared__ int bbase_s;
    int i = blockIdx.x * 256 + threadIdx.x;
    if (threadIdx.x == 0) {
        int i0 = blockIdx.x * 256;
        bbase_s = batch[i0 < N ? i0 : N - 1];
    }
    for (int t = threadIdx.x; t < 64; t += 256) bins[t] = 0.0f;
    float w = 0.0f;
    int b = -1;
    if (i < N) {
        float hi = h[i];
        float ws = expf(lrelu((att_src[0] + att_dst[0]) * hi));
        float dsum = denom[i] + ws;
        float nsum = num[i] + ws * hi;
        float xc = nsum / (dsum + 1e-16f) + bias[0];
        w = expf(xc);
        escore[i] = w;
        b = batch[i];
    }
    __syncthreads();
    if (i < N) {
        int off = b - bbase_s;
        if (off >= 0 && off < 64) atomicAdd(&bins[off], w);
        else                      atomicAdd(&gsum[b], w);
    }
    __syncthreads();
    for (int t = threadIdx.x; t < 64; t += 256)
        if (bins[t] != 0.0f) atomicAdd(&gsum[bbase_s + t], bins[t]);
}

// ---------------------------------------------------------------------------
extern "C" void kernel_launch(void* const* d_in, const int* in_sizes, int n_in,
                              void* d_out, int out_size, void* d_ws, size_t ws_size,
                              hipStream_t stream) {
    const float* x        = (const float*)d_in[0];
    const int*   eidx     = (const int*)d_in[1];
    const int*   batch    = (const int*)d_in[2];
    const float* W        = (const float*)d_in[3];
    const float* att_src  = (const float*)d_in[4];
    const float* att_dst  = (const float*)d_in[5];
    const float* bias     = (const float*)d_in[6];
    float*       gx       = (float*)d_out;

    const int N = in_sizes[2];
    const int E = in_sizes[1] / 2;
    const int G = out_size / DHID;
    const int NB = (N + BSZ - 1) >> BSZ_SHIFT;
    // padded per-bucket capacity: avg + 8192 (>30 sigma for uniform dst)
    const int CAP = ((E / NB + 8192) + 255) & ~255;

    const int* src = eidx;
    const int* dst = eidx + E;

    char* p = (char*)d_ws;
    auto alloc = [&](size_t bytes) {
        char* q = p;
        p += (bytes + 255) & ~(size_t)255;
        return q;
    };
    float* h      = (float*)alloc((size_t)N * 4);
    float* escore = (float*)alloc((size_t)N * 4);
    float* gsum   = (float*)alloc((size_t)G * 4);
    int*   startA = (int*)alloc((size_t)(G + 1) * 4);

    size_t fixed = (size_t)(p - (char*)d_ws);
    size_t need_full = fixed
        + 512 + (size_t)NB * 4                    // cursor
        + 512 + (size_t)NB * CAP * 4              // pairs (packed u32)
        + 512 + (size_t)NB * PSUB * 2 * BSZ * 4   // partials
        + 512 + (size_t)KSUB * G * DHID * 4;      // gxp

    // packed payload needs src to fit in (32 - BSZ_SHIFT) bits
    bool full = (NB <= MAXNB) && (N <= (1 << (32 - BSZ_SHIFT)))
             && (need_full + 4096 <= ws_size);

    int nRowBlk = (N + 31) / 32;          // 32 rows per 512-thread block
    int nBndBlk = (N + 511) / 512;

    if (full) {
        int*      cursor   = (int*)alloc((size_t)NB * 4);
        uint32_t* pairs    = (uint32_t*)alloc((size_t)NB * CAP * 4);
        float*    partials = (float*)alloc((size_t)NB * PSUB * 2 * BSZ * 4);
        float*    gxp      = (float*)alloc((size_t)KSUB * G * DHID * 4);

        int nScat = (E + SCHUNK - 1) / SCHUNK;

        hipMemsetAsync(cursor, 0, (size_t)NB * 4, stream);
        hipMemsetAsync(gsum, 0, (size_t)G * 4, stream);

        kM1<<<nScat + nRowBlk + nBndBlk, 512, 0, stream>>>(
            x, W, h, N, batch, startA, G,
            src, dst, E, NB, cursor, pairs, CAP, nScat, nRowBlk);
        k_accum<<<NB * PSUB, 256, 0, stream>>>(pairs, cursor, h,
                                               att_src, att_dst, partials,
                                               N, CAP);
        k3_scores_p<<<(N + 255) / 256, 256, 0, stream>>>(partials, h,
                                                         att_src, att_dst, bias,
                                                         batch, escore, gsum, N);
        k4_pool<<<G * KSUB, 256, 0, stream>>>(x, escore, gsum, startA, gxp, G);
        k5_merge<<<(G * DHID + 255) / 256, 256, 0, stream>>>(gxp, gx, G * DHID);
    } else {
        // fallback: direct global atomics; M1 with nScat=0 does h + bounds
        float* denom = (float*)alloc((size_t)N * 4);
        float* num   = (float*)alloc((size_t)N * 4);
        float* gxp   = (float*)alloc((size_t)KSUB * G * DHID * 4);
        int*   dummyCur = (int*)alloc(256);
        hipMemsetAsync(gsum, 0, (size_t)G * 4, stream);
        k0_zero_fb<<<(2 * N + 255) / 256, 256, 0, stream>>>(denom, 2 * N);
        kM1<<<nRowBlk + nBndBlk, 512, 0, stream>>>(
            x, W, h, N, batch, startA, G,
            src, dst, 0, 0, dummyCur, (uint32_t*)dummyCur, CAP, 0, nRowBlk);
        k2_edges_fb<<<(E + 255) / 256, 256, 0, stream>>>(src, dst, h,
                                                         att_src, att_dst,
                                                         denom, num, E);
        k3_scores_fb<<<(N + 255) / 256, 256, 0, stream>>>(denom, num, h,
                                                          att_src, att_dst, bias,
                                                          batch, escore, gsum, N);
        k4_pool<<<G * KSUB, 256, 0, stream>>>(x, escore, gsum, startA, gxp, G);
        k5_merge<<<(G * DHID + 255) / 256, 256, 0, stream>>>(gxp, gx, G * DHID);
    }
}

// Round 11
// 107.058 us; speedup vs baseline: 1.0673x; 1.0673x over previous
//
#include <hip/hip_runtime.h>
#include <stdint.h>

#define NEG_SLOPE 0.2f
#define DHID 256
#define BSZ_SHIFT 10                 // 1024 nodes per bucket
#define BSZ (1 << BSZ_SHIFT)
#define MAXNB 128                    // supports N <= 131072
#define PSUB 16                      // accumulate blocks per bucket
#define SCHUNK 4096                  // edges per scatter block (512 thr)

__device__ __forceinline__ float lrelu(float e) {
    return (e >= 0.0f) ? e : NEG_SLOPE * e;
}
__device__ __forceinline__ float dot4(float4 a, float4 b) {
    return a.x * b.x + a.y * b.y + a.z * b.z + a.w * b.w;
}

// ---------------------------------------------------------------------------
// k1 fused: row blocks compute h with 4 rows/wave (16 lanes/row, 4 float4
// loads per lane -> 16 independent loads in flight per wave); then bounds
// blocks; last block zeros gsum/cursor.
// NOTE: no device-scope fences (R8: per-block __threadfence = L2 storm).
// NOTE: no hipMemsetAsync for small buffers (R10: 2KB memset node = 59µs).
// ---------------------------------------------------------------------------
__global__ __launch_bounds__(256) void k1_h_bounds(
    const float* __restrict__ x, const float* __restrict__ W,
    float* __restrict__ h, int N,
    const int* __restrict__ batch, int* __restrict__ start, int G,
    float* __restrict__ gsum, int* __restrict__ cursor, int NB,
    int nRowBlk, int nBndBlk)
{
    if (blockIdx.x >= (unsigned)nRowBlk) {
        int rb = blockIdx.x - nRowBlk;
        if (rb == nBndBlk) {                     // zero block
            for (int t = threadIdx.x; t < G; t += 256) gsum[t] = 0.0f;
            for (int t = threadIdx.x; t < NB; t += 256) cursor[t] = 0;
            return;
        }
        int i = rb * 256 + threadIdx.x;
        if (i >= N) return;
        int b = batch[i];
        if (i == 0) {
            for (int g = 0; g <= b; ++g) start[g] = 0;
        } else {
            int bp = batch[i - 1];
            for (int g = bp + 1; g <= b; ++g) start[g] = i;
        }
        if (i == N - 1) {
            for (int g = b + 1; g <= G; ++g) start[g] = N;
        }
        return;
    }

    int wave = threadIdx.x >> 6;
    int lane = threadIdx.x & 63;
    int r = lane >> 4;                  // row within wave (0..3)
    int c = lane & 15;                  // 16 lanes per row
    int row = blockIdx.x * 16 + wave * 4 + r;
    if (row >= N) return;               // whole 16-lane group uniform

    float4 wv0 = *(const float4*)(W + c * 4);
    float4 wv1 = *(const float4*)(W + 64 + c * 4);
    float4 wv2 = *(const float4*)(W + 128 + c * 4);
    float4 wv3 = *(const float4*)(W + 192 + c * 4);
    const float* xr = x + (size_t)row * DHID;
    float4 a0 = *(const float4*)(xr + c * 4);
    float4 a1 = *(const float4*)(xr + 64 + c * 4);
    float4 a2 = *(const float4*)(xr + 128 + c * 4);
    float4 a3 = *(const float4*)(xr + 192 + c * 4);
    float s = dot4(a0, wv0) + dot4(a1, wv1) + dot4(a2, wv2) + dot4(a3, wv3);
    s += __shfl_xor(s, 1);
    s += __shfl_xor(s, 2);
    s += __shfl_xor(s, 4);
    s += __shfl_xor(s, 8);              // stays inside the 16-lane group
    if (c == 0) h[row] = s;
}

// ---------------------------------------------------------------------------
// k_scatter: packed 4B payload (src<<10 | dst&1023); edges reg-staged (read
// once), LDS-staged by bucket, coalesced write-out. 512 thr, SCHUNK 4096.
// Rank trick: hist-pass atomicAdd return IS the intra-block rank (no second
// LDS-atomic pass).
// ---------------------------------------------------------------------------
__global__ __launch_bounds__(512) void k_scatter(
    const int* __restrict__ src, const int* __restrict__ dst, int E, int NB,
    int* __restrict__ cursor, uint32_t* __restrict__ pairs, int CAP)
{
    __shared__ int cnt[MAXNB];
    __shared__ int loff[MAXNB];
    __shared__ int base_g[MAXNB];
    __shared__ uint32_t buf[SCHUNK];
    __shared__ uint8_t binOf[SCHUNK];

    int e0 = blockIdx.x * SCHUNK;
    int e1 = min(e0 + SCHUNK, E);
    int nch = e1 - e0;
    int t = threadIdx.x;

    int sv[8], dv[8], rk[8];
#pragma unroll
    for (int k = 0; k < 8; ++k) {
        int e = e0 + k * 512 + t;
        if (e < e1) { sv[k] = src[e]; dv[k] = dst[e]; }
    }

    for (int q = t; q < MAXNB; q += 512) cnt[q] = 0;
    __syncthreads();
#pragma unroll
    for (int k = 0; k < 8; ++k) {
        int e = e0 + k * 512 + t;
        if (e < e1) rk[k] = atomicAdd(&cnt[dv[k] >> BSZ_SHIFT], 1);
    }
    __syncthreads();
    // exclusive scan of cnt[0..127] by wave 0 (two chained 64-lane scans)
    if (t < 64) {
        int v0 = cnt[t], v1 = cnt[64 + t];
        int s0 = v0, s1 = v1;
#pragma unroll
        for (int d = 1; d < 64; d <<= 1) {
            int u0 = __shfl_up(s0, d);
            int u1 = __shfl_up(s1, d);
            if (t >= d) { s0 += u0; s1 += u1; }
        }
        int tot0 = __shfl(s0, 63);
        loff[t]      = s0 - v0;
        loff[64 + t] = s1 + tot0 - v1;
    }
    __syncthreads();
    for (int q = t; q < MAXNB; q += 512)
        if (q < NB && cnt[q] > 0) base_g[q] = atomicAdd(&cursor[q], cnt[q]);
    __syncthreads();
#pragma unroll
    for (int k = 0; k < 8; ++k) {
        int e = e0 + k * 512 + t;
        if (e < e1) {
            int bin = dv[k] >> BSZ_SHIFT;
            int q = loff[bin] + rk[k];
            buf[q] = ((uint32_t)sv[k] << BSZ_SHIFT) |
                     (uint32_t)(dv[k] & (BSZ - 1));
            binOf[q] = (uint8_t)bin;
        }
    }
    __syncthreads();
    for (int q = t; q < nch; q += 512) {
        int b = binOf[q];
        pairs[(size_t)b * CAP + base_g[b] + (q - loff[b])] = buf[q];
    }
}

// ---------------------------------------------------------------------------
// k_accum: block = (bucket b, sub s). pairs loaded as uint4 (4 edges/thread
// in flight -> 4 independent h[src] gathers); h[dst] from LDS slice;
// num/denom via LDS float atomics. partials layout: [(b*PSUB+s)][2][BSZ]
// ---------------------------------------------------------------------------
__global__ __launch_bounds__(256) void k_accum(
    const uint32_t* __restrict__ pairs, const int* __restrict__ cursor,
    const float* __restrict__ h,
    const float* __restrict__ att_src, const float* __restrict__ att_dst,
    float* __restrict__ partials, int N, int CAP)
{
    __shared__ float dacc[BSZ];
    __shared__ float nacc[BSZ];
    __shared__ float hbuf[BSZ];
    int b = blockIdx.x / PSUB;
    int s = blockIdx.x % PSUB;
    int base = b << BSZ_SHIFT;

    for (int t = threadIdx.x; t < BSZ; t += 256) {
        dacc[t] = 0.0f; nacc[t] = 0.0f;
        int gi = base + t;
        hbuf[t] = (gi < N) ? h[gi] : 0.0f;
    }
    __syncthreads();

    int count = cursor[b];
    int per = (((count + PSUB - 1) / PSUB) + 3) & ~3;   // ×4 aligned
    int i0 = s * per;
    int i1 = min(i0 + per, count);

    float as = att_src[0], ad = att_dst[0];
    const uint32_t* bp = pairs + (size_t)b * CAP;

    int i = i0 + threadIdx.x * 4;
    // vector main loop: 4 packed edges per thread per iteration
    for (; i + 3 < i1; i += 1024) {
        uint4 pr4 = *(const uint4*)(bp + i);
        float hs0 = h[pr4.x >> BSZ_SHIFT];
        float hs1 = h[pr4.y >> BSZ_SHIFT];
        float hs2 = h[pr4.z >> BSZ_SHIFT];
        float hs3 = h[pr4.w >> BSZ_SHIFT];
        int l0 = (int)(pr4.x & (BSZ - 1));
        int l1 = (int)(pr4.y & (BSZ - 1));
        int l2 = (int)(pr4.z & (BSZ - 1));
        int l3 = (int)(pr4.w & (BSZ - 1));
        float w0 = __expf(lrelu(as * hs0 + ad * hbuf[l0]));
        float w1 = __expf(lrelu(as * hs1 + ad * hbuf[l1]));
        float w2 = __expf(lrelu(as * hs2 + ad * hbuf[l2]));
        float w3 = __expf(lrelu(as * hs3 + ad * hbuf[l3]));
        atomicAdd(&dacc[l0], w0); atomicAdd(&nacc[l0], w0 * hs0);
        atomicAdd(&dacc[l1], w1); atomicAdd(&nacc[l1], w1 * hs1);
        atomicAdd(&dacc[l2], w2); atomicAdd(&nacc[l2], w2 * hs2);
        atomicAdd(&dacc[l3], w3); atomicAdd(&nacc[l3], w3 * hs3);
    }
    // tail (last partial quad of the sub-range)
    for (; i < i1; ++i) {
        uint32_t pr = bp[i];
        int ld = (int)(pr & (BSZ - 1));
        float hs = h[pr >> BSZ_SHIFT];
        float w = __expf(lrelu(as * hs + ad * hbuf[ld]));
        atomicAdd(&dacc[ld], w);
        atomicAdd(&nacc[ld], w * hs);
    }
    __syncthreads();
    float* out = partials + ((size_t)blockIdx.x * 2) * BSZ;
    for (int t = threadIdx.x; t < BSZ; t += 256) {
        out[t]       = dacc[t];
        out[BSZ + t] = nacc[t];
    }
}

// ---------------------------------------------------------------------------
// k3: merge partials + self-loop, escore = exp(num/denom + bias);
// LDS-binned gsum reduction (batch sorted).
// ---------------------------------------------------------------------------
__global__ __launch_bounds__(256) void k3_scores_p(
    const float* __restrict__ partials, const float* __restrict__ h,
    const float* __restrict__ att_src, const float* __restrict__ att_dst,
    const float* __restrict__ bias, const int* __restrict__ batch,
    float* __restrict__ escore, float* __restrict__ gsum, int N)
{
    __shared__ float bins[64];
    __shared__ int bbase_s;
    int i = blockIdx.x * 256 + threadIdx.x;
    if (threadIdx.x == 0) {
        int i0 = blockIdx.x * 256;
        bbase_s = batch[i0 < N ? i0 : N - 1];
    }
    for (int t = threadIdx.x; t < 64; t += 256) bins[t] = 0.0f;

    float w = 0.0f;
    int b = -1;
    if (i < N) {
        int bk = i >> BSZ_SHIFT;
        int pos = i & (BSZ - 1);
        float dsum = 0.0f, nsum = 0.0f;
#pragma unroll
        for (int p = 0; p < PSUB; ++p) {
            const float* pp = partials + ((size_t)(bk * PSUB + p) * 2) * BSZ;
            dsum += pp[pos];
            nsum += pp[BSZ + pos];
        }
        float hi = h[i];
        float e0 = lrelu((att_src[0] + att_dst[0]) * hi);
        float ws = __expf(e0);
        dsum += ws;
        nsum += ws * hi;
        float xc = nsum / (dsum + 1e-16f) + bias[0];
        w = __expf(xc);
        escore[i] = w;
        b = batch[i];
    }
    __syncthreads();
    if (i < N) {
        int off = b - bbase_s;
        if (off >= 0 && off < 64) atomicAdd(&bins[off], w);
        else                      atomicAdd(&gsum[b], w);
    }
    __syncthreads();
    for (int t = threadIdx.x; t < 64; t += 256)
        if (bins[t] != 0.0f) atomicAdd(&gsum[bbase_s + t], bins[t]);
}

// ---------------------------------------------------------------------------
// k4: ONE 1024-thread block per graph, 16 rows in flight, writes gx directly
// (no gxp/k5). Grid = G = 512 blocks = 2 blocks/CU = full wave occupancy.
// ---------------------------------------------------------------------------
__global__ __launch_bounds__(1024) void k4_pool(
    const float* __restrict__ x, const float* __restrict__ escore,
    const float* __restrict__ gsum, const int* __restrict__ start,
    float* __restrict__ gx)
{
    __shared__ float4 red[1024];
    int g = blockIdx.x;
    int st = start[g], en = start[g + 1];
    float inv = 1.0f / (gsum[g] + 1e-16f);
    int tid    = threadIdx.x;
    int col4   = (tid & 63) << 2;
    int rowOff = tid >> 6;          // 0..15

    float4 acc = make_float4(0.f, 0.f, 0.f, 0.f);
    for (int i = st + rowOff; i < en; i += 16) {
        float sc = escore[i] * inv;
        float4 v = *(const float4*)(x + (size_t)i * DHID + col4);
        acc.x += v.x * sc; acc.y += v.y * sc;
        acc.z += v.z * sc; acc.w += v.w * sc;
    }

    red[tid] = acc;
    __syncthreads();
    if (tid < 64) {
        float4 r = red[tid];
#pragma unroll
        for (int k = 1; k < 16; ++k) {
            float4 v = red[tid + 64 * k];
            r.x += v.x; r.y += v.y; r.z += v.z; r.w += v.w;
        }
        *(float4*)(gx + (size_t)g * DHID + col4) = r;
    }
}

// ---------------------------------------------------------------------------
// Fallback path (ws too small): direct global atomics.
// ---------------------------------------------------------------------------
__global__ __launch_bounds__(256) void k0_zero_fb(float* __restrict__ p, int n) {
    int i = blockIdx.x * 256 + threadIdx.x;
    if (i < n) p[i] = 0.0f;
}
__global__ __launch_bounds__(256) void k2_edges_fb(
    const int* __restrict__ src, const int* __restrict__ dst,
    const float* __restrict__ h,
    const float* __restrict__ att_src, const float* __restrict__ att_dst,
    float* __restrict__ denom, float* __restrict__ num, int E)
{
    int i = blockIdx.x * 256 + threadIdx.x;
    if (i >= E) return;
    int s = src[i], d = dst[i];
    float as = att_src[0], ad = att_dst[0];
    float hs = h[s];
    float w = expf(lrelu(as * hs + ad * h[d]));
    atomicAdd(&denom[d], w);
    atomicAdd(&num[d],   w * hs);
}
__global__ __launch_bounds__(256) void k3_scores_fb(
    const float* __restrict__ denom, const float* __restrict__ num,
    const float* __restrict__ h,
    const float* __restrict__ att_src, const float* __restrict__ att_dst,
    const float* __restrict__ bias, const int* __restrict__ batch,
    float* __restrict__ escore, float* __restrict__ gsum, int N)
{
    __shared__ float bins[64];
    __shared__ int bbase_s;
    int i = blockIdx.x * 256 + threadIdx.x;
    if (threadIdx.x == 0) {
        int i0 = blockIdx.x * 256;
        bbase_s = batch[i0 < N ? i0 : N - 1];
    }
    for (int t = threadIdx.x; t < 64; t += 256) bins[t] = 0.0f;
    float w = 0.0f;
    int b = -1;
    if (i < N) {
        float hi = h[i];
        float ws = expf(lrelu((att_src[0] + att_dst[0]) * hi));
        float dsum = denom[i] + ws;
        float nsum = num[i] + ws * hi;
        float xc = nsum / (dsum + 1e-16f) + bias[0];
        w = expf(xc);
        escore[i] = w;
        b = batch[i];
    }
    __syncthreads();
    if (i < N) {
        int off = b - bbase_s;
        if (off >= 0 && off < 64) atomicAdd(&bins[off], w);
        else                      atomicAdd(&gsum[b], w);
    }
    __syncthreads();
    for (int t = threadIdx.x; t < 64; t += 256)
        if (bins[t] != 0.0f) atomicAdd(&gsum[bbase_s + t], bins[t]);
}

// ---------------------------------------------------------------------------
extern "C" void kernel_launch(void* const* d_in, const int* in_sizes, int n_in,
                              void* d_out, int out_size, void* d_ws, size_t ws_size,
                              hipStream_t stream) {
    const float* x        = (const float*)d_in[0];
    const int*   eidx     = (const int*)d_in[1];
    const int*   batch    = (const int*)d_in[2];
    const float* W        = (const float*)d_in[3];
    const float* att_src  = (const float*)d_in[4];
    const float* att_dst  = (const float*)d_in[5];
    const float* bias     = (const float*)d_in[6];
    float*       gx       = (float*)d_out;

    const int N = in_sizes[2];
    const int E = in_sizes[1] / 2;
    const int G = out_size / DHID;
    const int NB = (N + BSZ - 1) >> BSZ_SHIFT;
    // padded per-bucket capacity: avg + 8192 (>30 sigma for uniform dst)
    const int CAP = ((E / NB + 8192) + 255) & ~255;

    const int* src = eidx;
    const int* dst = eidx + E;

    char* p = (char*)d_ws;
    auto alloc = [&](size_t bytes) {
        char* q = p;
        p += (bytes + 255) & ~(size_t)255;
        return q;
    };
    float* h      = (float*)alloc((size_t)N * 4);
    float* escore = (float*)alloc((size_t)N * 4);
    float* gsum   = (float*)alloc((size_t)G * 4);
    int*   startA = (int*)alloc((size_t)(G + 1) * 4);

    size_t fixed = (size_t)(p - (char*)d_ws);
    size_t need_full = fixed
        + 512 + (size_t)NB * 4                    // cursor
        + 512 + (size_t)NB * CAP * 4              // pairs (packed u32)
        + 512 + (size_t)NB * PSUB * 2 * BSZ * 4;  // partials

    // packed payload needs src to fit in (32 - BSZ_SHIFT) bits
    bool full = (NB <= MAXNB) && (N <= (1 << (32 - BSZ_SHIFT)))
             && (need_full + 4096 <= ws_size);

    int nRowBlk = (N + 15) / 16;
    int nBndBlk = (N + 255) / 256;

    if (full) {
        int*      cursor   = (int*)alloc((size_t)NB * 4);
        uint32_t* pairs    = (uint32_t*)alloc((size_t)NB * CAP * 4);
        float*    partials = (float*)alloc((size_t)NB * PSUB * 2 * BSZ * 4);

        int sgrid = (E + SCHUNK - 1) / SCHUNK;

        k1_h_bounds<<<nRowBlk + nBndBlk + 1, 256, 0, stream>>>(
            x, W, h, N, batch, startA, G, gsum, cursor, NB, nRowBlk, nBndBlk);
        k_scatter<<<sgrid, 512, 0, stream>>>(src, dst, E, NB, cursor,
                                             pairs, CAP);
        k_accum<<<NB * PSUB, 256, 0, stream>>>(pairs, cursor, h,
                                               att_src, att_dst, partials,
                                               N, CAP);
        k3_scores_p<<<(N + 255) / 256, 256, 0, stream>>>(partials, h,
                                                         att_src, att_dst, bias,
                                                         batch, escore, gsum, N);
        k4_pool<<<G, 1024, 0, stream>>>(x, escore, gsum, startA, gx);
    } else {
        // fallback: direct global atomics
        float* denom = (float*)alloc((size_t)N * 4);
        float* num   = (float*)alloc((size_t)N * 4);
        int*   dummyCur = (int*)alloc(256);
        k0_zero_fb<<<(2 * N + 255) / 256, 256, 0, stream>>>(denom, 2 * N);
        k1_h_bounds<<<nRowBlk + nBndBlk + 1, 256, 0, stream>>>(
            x, W, h, N, batch, startA, G, gsum, dummyCur, 0, nRowBlk, nBndBlk);
        k2_edges_fb<<<(E + 255) / 256, 256, 0, stream>>>(src, dst, h,
                                                         att_src, att_dst,
                                                         denom, num, E);
        k3_scores_fb<<<(N + 255) / 256, 256, 0, stream>>>(denom, num, h,
                                                          att_src, att_dst, bias,
                                                          batch, escore, gsum, N);
        k4_pool<<<G, 1024, 0, stream>>>(x, escore, gsum, startA, gx);
    }
}

// Round 12
// 105.433 us; speedup vs baseline: 1.0837x; 1.0154x over previous
//
#include <hip/hip_runtime.h>
#include <stdint.h>

#define NEG_SLOPE 0.2f
#define DHID 256
#define BSZ_SHIFT 10                 // 1024 nodes per bucket
#define BSZ (1 << BSZ_SHIFT)
#define MAXNB 128                    // supports N <= 131072
#define PSUB 16                      // accumulate blocks per bucket
#define SCHUNK 4096                  // edges per scatter block (512 thr)

__device__ __forceinline__ float lrelu(float e) {
    return (e >= 0.0f) ? e : NEG_SLOPE * e;
}
__device__ __forceinline__ float dot4(float4 a, float4 b) {
    return a.x * b.x + a.y * b.y + a.z * b.z + a.w * b.w;
}

// ---------------------------------------------------------------------------
// k1 fused: row blocks compute h with 4 rows/wave (16 lanes/row, 4 float4
// loads per lane -> 16 independent loads in flight per wave); then bounds
// blocks; last block zeros cursor.
// NOTE: no device-scope fences (R8: per-block __threadfence = L2 storm).
// NOTE: no hipMemsetAsync for small buffers (R10: 2KB memset node = 59µs).
// ---------------------------------------------------------------------------
__global__ __launch_bounds__(256) void k1_h_bounds(
    const float* __restrict__ x, const float* __restrict__ W,
    float* __restrict__ h, int N,
    const int* __restrict__ batch, int* __restrict__ start, int G,
    int* __restrict__ cursor, int NB,
    int nRowBlk, int nBndBlk)
{
    if (blockIdx.x >= (unsigned)nRowBlk) {
        int rb = blockIdx.x - nRowBlk;
        if (rb == nBndBlk) {                     // zero block
            for (int t = threadIdx.x; t < NB; t += 256) cursor[t] = 0;
            return;
        }
        int i = rb * 256 + threadIdx.x;
        if (i >= N) return;
        int b = batch[i];
        if (i == 0) {
            for (int g = 0; g <= b; ++g) start[g] = 0;
        } else {
            int bp = batch[i - 1];
            for (int g = bp + 1; g <= b; ++g) start[g] = i;
        }
        if (i == N - 1) {
            for (int g = b + 1; g <= G; ++g) start[g] = N;
        }
        return;
    }

    int wave = threadIdx.x >> 6;
    int lane = threadIdx.x & 63;
    int r = lane >> 4;                  // row within wave (0..3)
    int c = lane & 15;                  // 16 lanes per row
    int row = blockIdx.x * 16 + wave * 4 + r;
    if (row >= N) return;               // whole 16-lane group uniform

    float4 wv0 = *(const float4*)(W + c * 4);
    float4 wv1 = *(const float4*)(W + 64 + c * 4);
    float4 wv2 = *(const float4*)(W + 128 + c * 4);
    float4 wv3 = *(const float4*)(W + 192 + c * 4);
    const float* xr = x + (size_t)row * DHID;
    float4 a0 = *(const float4*)(xr + c * 4);
    float4 a1 = *(const float4*)(xr + 64 + c * 4);
    float4 a2 = *(const float4*)(xr + 128 + c * 4);
    float4 a3 = *(const float4*)(xr + 192 + c * 4);
    float s = dot4(a0, wv0) + dot4(a1, wv1) + dot4(a2, wv2) + dot4(a3, wv3);
    s += __shfl_xor(s, 1);
    s += __shfl_xor(s, 2);
    s += __shfl_xor(s, 4);
    s += __shfl_xor(s, 8);              // stays inside the 16-lane group
    if (c == 0) h[row] = s;
}

// ---------------------------------------------------------------------------
// k_scatter: packed 4B payload (src<<10 | dst&1023); edges reg-staged (read
// once), LDS-staged by bucket, coalesced write-out. 512 thr, SCHUNK 4096.
// Rank trick: hist-pass atomicAdd return IS the intra-block rank.
// ---------------------------------------------------------------------------
__global__ __launch_bounds__(512) void k_scatter(
    const int* __restrict__ src, const int* __restrict__ dst, int E, int NB,
    int* __restrict__ cursor, uint32_t* __restrict__ pairs, int CAP)
{
    __shared__ int cnt[MAXNB];
    __shared__ int loff[MAXNB];
    __shared__ int base_g[MAXNB];
    __shared__ uint32_t buf[SCHUNK];
    __shared__ uint8_t binOf[SCHUNK];

    int e0 = blockIdx.x * SCHUNK;
    int e1 = min(e0 + SCHUNK, E);
    int nch = e1 - e0;
    int t = threadIdx.x;

    int sv[8], dv[8], rk[8];
#pragma unroll
    for (int k = 0; k < 8; ++k) {
        int e = e0 + k * 512 + t;
        if (e < e1) { sv[k] = src[e]; dv[k] = dst[e]; }
    }

    for (int q = t; q < MAXNB; q += 512) cnt[q] = 0;
    __syncthreads();
#pragma unroll
    for (int k = 0; k < 8; ++k) {
        int e = e0 + k * 512 + t;
        if (e < e1) rk[k] = atomicAdd(&cnt[dv[k] >> BSZ_SHIFT], 1);
    }
    __syncthreads();
    // exclusive scan of cnt[0..127] by wave 0 (two chained 64-lane scans)
    if (t < 64) {
        int v0 = cnt[t], v1 = cnt[64 + t];
        int s0 = v0, s1 = v1;
#pragma unroll
        for (int d = 1; d < 64; d <<= 1) {
            int u0 = __shfl_up(s0, d);
            int u1 = __shfl_up(s1, d);
            if (t >= d) { s0 += u0; s1 += u1; }
        }
        int tot0 = __shfl(s0, 63);
        loff[t]      = s0 - v0;
        loff[64 + t] = s1 + tot0 - v1;
    }
    __syncthreads();
    for (int q = t; q < MAXNB; q += 512)
        if (q < NB && cnt[q] > 0) base_g[q] = atomicAdd(&cursor[q], cnt[q]);
    __syncthreads();
#pragma unroll
    for (int k = 0; k < 8; ++k) {
        int e = e0 + k * 512 + t;
        if (e < e1) {
            int bin = dv[k] >> BSZ_SHIFT;
            int q = loff[bin] + rk[k];
            buf[q] = ((uint32_t)sv[k] << BSZ_SHIFT) |
                     (uint32_t)(dv[k] & (BSZ - 1));
            binOf[q] = (uint8_t)bin;
        }
    }
    __syncthreads();
    for (int q = t; q < nch; q += 512) {
        int b = binOf[q];
        pairs[(size_t)b * CAP + base_g[b] + (q - loff[b])] = buf[q];
    }
}

// ---------------------------------------------------------------------------
// k_accum: block = (bucket b, sub s). pairs loaded as uint4 (4 edges/thread
// in flight -> 4 independent h[src] gathers); h[dst] from LDS slice;
// num/denom via LDS float atomics. partials layout: [(b*PSUB+s)][2][BSZ]
// ---------------------------------------------------------------------------
__global__ __launch_bounds__(256) void k_accum(
    const uint32_t* __restrict__ pairs, const int* __restrict__ cursor,
    const float* __restrict__ h,
    const float* __restrict__ att_src, const float* __restrict__ att_dst,
    float* __restrict__ partials, int N, int CAP)
{
    __shared__ float dacc[BSZ];
    __shared__ float nacc[BSZ];
    __shared__ float hbuf[BSZ];
    int b = blockIdx.x / PSUB;
    int s = blockIdx.x % PSUB;
    int base = b << BSZ_SHIFT;

    for (int t = threadIdx.x; t < BSZ; t += 256) {
        dacc[t] = 0.0f; nacc[t] = 0.0f;
        int gi = base + t;
        hbuf[t] = (gi < N) ? h[gi] : 0.0f;
    }
    __syncthreads();

    int count = cursor[b];
    int per = (((count + PSUB - 1) / PSUB) + 3) & ~3;   // ×4 aligned
    int i0 = s * per;
    int i1 = min(i0 + per, count);

    float as = att_src[0], ad = att_dst[0];
    const uint32_t* bp = pairs + (size_t)b * CAP;

    int i = i0 + threadIdx.x * 4;
    for (; i + 3 < i1; i += 1024) {
        uint4 pr4 = *(const uint4*)(bp + i);
        float hs0 = h[pr4.x >> BSZ_SHIFT];
        float hs1 = h[pr4.y >> BSZ_SHIFT];
        float hs2 = h[pr4.z >> BSZ_SHIFT];
        float hs3 = h[pr4.w >> BSZ_SHIFT];
        int l0 = (int)(pr4.x & (BSZ - 1));
        int l1 = (int)(pr4.y & (BSZ - 1));
        int l2 = (int)(pr4.z & (BSZ - 1));
        int l3 = (int)(pr4.w & (BSZ - 1));
        float w0 = __expf(lrelu(as * hs0 + ad * hbuf[l0]));
        float w1 = __expf(lrelu(as * hs1 + ad * hbuf[l1]));
        float w2 = __expf(lrelu(as * hs2 + ad * hbuf[l2]));
        float w3 = __expf(lrelu(as * hs3 + ad * hbuf[l3]));
        atomicAdd(&dacc[l0], w0); atomicAdd(&nacc[l0], w0 * hs0);
        atomicAdd(&dacc[l1], w1); atomicAdd(&nacc[l1], w1 * hs1);
        atomicAdd(&dacc[l2], w2); atomicAdd(&nacc[l2], w2 * hs2);
        atomicAdd(&dacc[l3], w3); atomicAdd(&nacc[l3], w3 * hs3);
    }
    for (; i < i1; ++i) {
        uint32_t pr = bp[i];
        int ld = (int)(pr & (BSZ - 1));
        float hs = h[pr >> BSZ_SHIFT];
        float w = __expf(lrelu(as * hs + ad * hbuf[ld]));
        atomicAdd(&dacc[ld], w);
        atomicAdd(&nacc[ld], w * hs);
    }
    __syncthreads();
    float* out = partials + ((size_t)blockIdx.x * 2) * BSZ;
    for (int t = threadIdx.x; t < BSZ; t += 256) {
        out[t]       = dacc[t];
        out[BSZ + t] = nacc[t];
    }
}

// ---------------------------------------------------------------------------
// k3: merge partials + self-loop, escore = exp(num/denom + bias).
// Pure elementwise now — gsum is NOT materialized (normalization is linear,
// k4 divides by the in-pass weight sum instead).
// ---------------------------------------------------------------------------
__global__ __launch_bounds__(256) void k3_scores_p(
    const float* __restrict__ partials, const float* __restrict__ h,
    const float* __restrict__ att_src, const float* __restrict__ att_dst,
    const float* __restrict__ bias,
    float* __restrict__ escore, int N)
{
    int i = blockIdx.x * 256 + threadIdx.x;
    if (i >= N) return;
    int bk = i >> BSZ_SHIFT;
    int pos = i & (BSZ - 1);
    float dsum = 0.0f, nsum = 0.0f;
#pragma unroll
    for (int p = 0; p < PSUB; ++p) {
        const float* pp = partials + ((size_t)(bk * PSUB + p) * 2) * BSZ;
        dsum += pp[pos];
        nsum += pp[BSZ + pos];
    }
    float hi = h[i];
    float e0 = lrelu((att_src[0] + att_dst[0]) * hi);
    float ws = __expf(e0);
    dsum += ws;
    nsum += ws * hi;
    float xc = nsum / (dsum + 1e-16f) + bias[0];
    escore[i] = __expf(xc);
}

// ---------------------------------------------------------------------------
// k4: ONE 1024-thread block per graph; accumulates Σ x·escore AND Σ escore
// in the same pass, divides at the end (softmax normalization is linear).
// 2-deep unroll -> 2 independent float4 loads in flight per thread.
// ---------------------------------------------------------------------------
__global__ __launch_bounds__(1024) void k4_pool(
    const float* __restrict__ x, const float* __restrict__ escore,
    const int* __restrict__ start, float* __restrict__ gx)
{
    __shared__ float4 red[1024];
    __shared__ float redw[1024];
    int g = blockIdx.x;
    int st = start[g], en = start[g + 1];
    int tid    = threadIdx.x;
    int col4   = (tid & 63) << 2;
    int rowOff = tid >> 6;          // 0..15

    float4 acc = make_float4(0.f, 0.f, 0.f, 0.f);
    float wsum = 0.0f;
    int i = st + rowOff;
    for (; i + 16 < en; i += 32) {
        float sc0 = escore[i];
        float sc1 = escore[i + 16];
        float4 v0 = *(const float4*)(x + (size_t)i * DHID + col4);
        float4 v1 = *(const float4*)(x + (size_t)(i + 16) * DHID + col4);
        acc.x += v0.x * sc0 + v1.x * sc1;
        acc.y += v0.y * sc0 + v1.y * sc1;
        acc.z += v0.z * sc0 + v1.z * sc1;
        acc.w += v0.w * sc0 + v1.w * sc1;
        wsum += sc0 + sc1;
    }
    if (i < en) {
        float sc = escore[i];
        float4 v = *(const float4*)(x + (size_t)i * DHID + col4);
        acc.x += v.x * sc; acc.y += v.y * sc;
        acc.z += v.z * sc; acc.w += v.w * sc;
        wsum += sc;
    }

    red[tid] = acc;
    redw[tid] = wsum;
    __syncthreads();
    if (tid < 64) {
        float4 r = red[tid];
        float wtot = redw[tid];
#pragma unroll
        for (int k = 1; k < 16; ++k) {
            float4 v = red[tid + 64 * k];
            r.x += v.x; r.y += v.y; r.z += v.z; r.w += v.w;
            wtot += redw[tid + 64 * k];
        }
        float inv = 1.0f / (wtot + 1e-16f);
        r.x *= inv; r.y *= inv; r.z *= inv; r.w *= inv;
        *(float4*)(gx + (size_t)g * DHID + col4) = r;
    }
}

// ---------------------------------------------------------------------------
// Fallback path (ws too small): direct global atomics.
// ---------------------------------------------------------------------------
__global__ __launch_bounds__(256) void k0_zero_fb(float* __restrict__ p, int n) {
    int i = blockIdx.x * 256 + threadIdx.x;
    if (i < n) p[i] = 0.0f;
}
__global__ __launch_bounds__(256) void k2_edges_fb(
    const int* __restrict__ src, const int* __restrict__ dst,
    const float* __restrict__ h,
    const float* __restrict__ att_src, const float* __restrict__ att_dst,
    float* __restrict__ denom, float* __restrict__ num, int E)
{
    int i = blockIdx.x * 256 + threadIdx.x;
    if (i >= E) return;
    int s = src[i], d = dst[i];
    float as = att_src[0], ad = att_dst[0];
    float hs = h[s];
    float w = expf(lrelu(as * hs + ad * h[d]));
    atomicAdd(&denom[d], w);
    atomicAdd(&num[d],   w * hs);
}
__global__ __launch_bounds__(256) void k3_scores_fb(
    const float* __restrict__ denom, const float* __restrict__ num,
    const float* __restrict__ h,
    const float* __restrict__ att_src, const float* __restrict__ att_dst,
    const float* __restrict__ bias,
    float* __restrict__ escore, int N)
{
    int i = blockIdx.x * 256 + threadIdx.x;
    if (i >= N) return;
    float hi = h[i];
    float ws = expf(lrelu((att_src[0] + att_dst[0]) * hi));
    float dsum = denom[i] + ws;
    float nsum = num[i] + ws * hi;
    float xc = nsum / (dsum + 1e-16f) + bias[0];
    escore[i] = expf(xc);
}

// ---------------------------------------------------------------------------
extern "C" void kernel_launch(void* const* d_in, const int* in_sizes, int n_in,
                              void* d_out, int out_size, void* d_ws, size_t ws_size,
                              hipStream_t stream) {
    const float* x        = (const float*)d_in[0];
    const int*   eidx     = (const int*)d_in[1];
    const int*   batch    = (const int*)d_in[2];
    const float* W        = (const float*)d_in[3];
    const float* att_src  = (const float*)d_in[4];
    const float* att_dst  = (const float*)d_in[5];
    const float* bias     = (const float*)d_in[6];
    float*       gx       = (float*)d_out;

    const int N = in_sizes[2];
    const int E = in_sizes[1] / 2;
    const int G = out_size / DHID;
    const int NB = (N + BSZ - 1) >> BSZ_SHIFT;
    // padded per-bucket capacity: avg + 8192 (>30 sigma for uniform dst)
    const int CAP = ((E / NB + 8192) + 255) & ~255;

    const int* src = eidx;
    const int* dst = eidx + E;

    char* p = (char*)d_ws;
    auto alloc = [&](size_t bytes) {
        char* q = p;
        p += (bytes + 255) & ~(size_t)255;
        return q;
    };
    float* h      = (float*)alloc((size_t)N * 4);
    float* escore = (float*)alloc((size_t)N * 4);
    int*   startA = (int*)alloc((size_t)(G + 1) * 4);

    size_t fixed = (size_t)(p - (char*)d_ws);
    size_t need_full = fixed
        + 512 + (size_t)NB * 4                    // cursor
        + 512 + (size_t)NB * CAP * 4              // pairs (packed u32)
        + 512 + (size_t)NB * PSUB * 2 * BSZ * 4;  // partials

    // packed payload needs src to fit in (32 - BSZ_SHIFT) bits
    bool full = (NB <= MAXNB) && (N <= (1 << (32 - BSZ_SHIFT)))
             && (need_full + 4096 <= ws_size);

    int nRowBlk = (N + 15) / 16;
    int nBndBlk = (N + 255) / 256;

    if (full) {
        int*      cursor   = (int*)alloc((size_t)NB * 4);
        uint32_t* pairs    = (uint32_t*)alloc((size_t)NB * CAP * 4);
        float*    partials = (float*)alloc((size_t)NB * PSUB * 2 * BSZ * 4);

        int sgrid = (E + SCHUNK - 1) / SCHUNK;

        k1_h_bounds<<<nRowBlk + nBndBlk + 1, 256, 0, stream>>>(
            x, W, h, N, batch, startA, G, cursor, NB, nRowBlk, nBndBlk);
        k_scatter<<<sgrid, 512, 0, stream>>>(src, dst, E, NB, cursor,
                                             pairs, CAP);
        k_accum<<<NB * PSUB, 256, 0, stream>>>(pairs, cursor, h,
                                               att_src, att_dst, partials,
                                               N, CAP);
        k3_scores_p<<<(N + 255) / 256, 256, 0, stream>>>(partials, h,
                                                         att_src, att_dst, bias,
                                                         escore, N);
        k4_pool<<<G, 1024, 0, stream>>>(x, escore, startA, gx);
    } else {
        // fallback: direct global atomics
        float* denom = (float*)alloc((size_t)N * 4);
        float* num   = (float*)alloc((size_t)N * 4);
        int*   dummyCur = (int*)alloc(256);
        k0_zero_fb<<<(2 * N + 255) / 256, 256, 0, stream>>>(denom, 2 * N);
        k1_h_bounds<<<nRowBlk + nBndBlk + 1, 256, 0, stream>>>(
            x, W, h, N, batch, startA, G, dummyCur, 0, nRowBlk, nBndBlk);
        k2_edges_fb<<<(E + 255) / 256, 256, 0, stream>>>(src, dst, h,
                                                         att_src, att_dst,
                                                         denom, num, E);
        k3_scores_fb<<<(N + 255) / 256, 256, 0, stream>>>(denom, num, h,
                                                          att_src, att_dst, bias,
                                                          escore, N);
        k4_pool<<<G, 1024, 0, stream>>>(x, escore, startA, gx);
    }
}